// Round 17
// baseline (2903.692 us; speedup 1.0000x reference)
//
#include <hip/hip_runtime.h>
#include <math.h>

#define B_ 32
#define L_ 512
#define S_ 37
#define STATIC_ 8
#define D_ 768
#define DI_ 1536
#define N_ 16
#define DTR_ 48
#define NL_ 4
#define V_ 32
#define ROWS_ (B_*L_)      // 16384
#define CB_ 8              // batch chunk
#define CROWS_ (CB_*L_)    // 4096
#define NCH_ (B_/CB_)      // 4
#define KE_ 96             // padded embed K (74 -> 96)
#define TCH_ 64            // scan LDS chunk (timesteps)
#define NCHT_ (L_/TCH_)    // 8 chunks
#define TP4_ 68            // padded row stride (u32) for scan LDS
#define KS_ 4              // xproj split-K slices
#define KSL_ (DI_/KS_)     // 384

typedef __bf16 bf16;
typedef __bf16 bf16x8 __attribute__((ext_vector_type(8)));
typedef __bf16 bf16x4 __attribute__((ext_vector_type(4)));
typedef __bf16 bf16x2 __attribute__((ext_vector_type(2)));
typedef float f32x4 __attribute__((ext_vector_type(4)));

typedef __attribute__((address_space(3))) void lds_void;
typedef __attribute__((address_space(1))) const void gmem_void;

__device__ __forceinline__ void gld16(const void* g, void* l) {
    __builtin_amdgcn_global_load_lds((gmem_void*)g, (lds_void*)l, 16, 0, 0);
}

__device__ __forceinline__ float silu_(float x) { return x / (1.f + __expf(-x)); }
__device__ __forceinline__ float softplus_(float x) {
    return fmaxf(x, 0.f) + __logf(1.f + __expf(-fabsf(x)));
}
__device__ __forceinline__ unsigned pack_bf2_(float a, float b) {
    bf16x2 v{(bf16)a, (bf16)b};
    return __builtin_bit_cast(unsigned, v);
}
template<int CTRL>
__device__ __forceinline__ float dpp_add_(float p) {
    int vi = __builtin_amdgcn_update_dpp(0, __builtin_bit_cast(int, p),
                                         CTRL, 0xF, 0xF, true);
    return p + __builtin_bit_cast(float, vi);
}

// ================= bf16 MFMA GEMM: C[M,*] = A[M,K] @ W[Nalloc,K]^T =================
// LDS uses XOR-swizzled 16B segments: data (row, seg) lives at slot (row, seg ^ ((row>>1)&3)).
// Staging permutes per-lane GLOBAL pointers (LDS side stays contiguous for global_load_lds);
// fragment reads XOR the quad index -> 2-way bank aliasing (free) instead of 8-way.
// MODE 0: f32 out (+addsrc), stride Nstore   [1-D grid, XCD swizzle; ntn = n-tiles]
// MODE 1: bf16 out, stride Nstore            [1-D grid, XCD swizzle]
// MODE 2: dt epilogue: swg[m*DI_+n] = pack(du,dtv)  [1-D grid, XCD swizzle]
// MODE 4: split-K partial (2-D grid)
template<int MODE>
__global__ __launch_bounds__(256) void gemm_mfma(
    const bf16* __restrict__ A, const bf16* __restrict__ W,
    const float* __restrict__ addsrc, void* __restrict__ Cv,
    int Nstore, int K, int ntn,
    const float* __restrict__ dt_bias, unsigned* __restrict__ swg,
    float* __restrict__ pbuf, const bf16* __restrict__ uref)
{
    __shared__ bf16 As[128 * 32];
    __shared__ bf16 Bs[128 * 32];
    const int tid = threadIdx.x;

    int m0, n0, kbeg, kend;
    if (MODE == 4) {
        m0 = blockIdx.y * 128; n0 = 0;
        kbeg = blockIdx.x * KSL_; kend = kbeg + KSL_;
    } else {
        int bid = blockIdx.x;
        int xcd = bid & 7, slot = bid >> 3;
        int Mtiles = gridDim.x / ntn;
        int mband = Mtiles >> 3;
        int m_tile = xcd * mband + slot / ntn;
        int n_tile = slot % ntn;
        m0 = m_tile * 128; n0 = n_tile * 128;
        kbeg = 0; kend = K;
    }

    f32x4 acc[4][4];
    #pragma unroll
    for (int i = 0; i < 4; i++)
        #pragma unroll
        for (int j = 0; j < 4; j++)
            acc[i][j] = f32x4{0.f, 0.f, 0.f, 0.f};

    const int srow = tid >> 2;
    const int sseg = (tid & 3) ^ ((srow >> 1) & 3);   // XOR-swizzled source segment
    const bf16* ag = A + (size_t)(m0 + srow) * K + sseg * 8;
    const bf16* wg = W + (size_t)(n0 + srow) * K + sseg * 8;
    char* lA = (char*)As + tid * 16;
    char* lB = (char*)Bs + tid * 16;

    const int lane = tid & 63, wv = tid >> 6;
    const int wr = wv >> 1, wc = wv & 1;
    const int colL = lane & 15, quad = lane >> 4;
    const int qsw = quad ^ ((colL >> 1) & 3);         // swizzled read segment
    const bf16* aRd = As + (wr * 64 + colL) * 32 + qsw * 8;
    const bf16* bRd = Bs + (wc * 64 + colL) * 32 + qsw * 8;

    for (int kt = kbeg; kt < kend; kt += 32) {
        gld16(ag + kt, lA);
        gld16(ag + kt + (size_t)64 * K, lA + 4096);
        gld16(wg + kt, lB);
        gld16(wg + kt + (size_t)64 * K, lB + 4096);
        __syncthreads();
        bf16x8 fa[4], fb[4];
        #pragma unroll
        for (int i = 0; i < 4; i++) fa[i] = *(const bf16x8*)(aRd + i * 16 * 32);
        #pragma unroll
        for (int j = 0; j < 4; j++) fb[j] = *(const bf16x8*)(bRd + j * 16 * 32);
        #pragma unroll
        for (int i = 0; i < 4; i++)
            #pragma unroll
            for (int j = 0; j < 4; j++)
                acc[i][j] = __builtin_amdgcn_mfma_f32_16x16x32_bf16(fa[i], fb[j], acc[i][j], 0, 0, 0);
        __syncthreads();
    }

    float* Cf = (float*)Cv;
    bf16*  Cb = (bf16*)Cv;
    #pragma unroll
    for (int i = 0; i < 4; i++) {
        #pragma unroll
        for (int j = 0; j < 4; j++) {
            int n = n0 + wc * 64 + j * 16 + colL;
            #pragma unroll
            for (int r = 0; r < 4; r++) {
                int m = m0 + wr * 64 + i * 16 + quad * 4 + r;
                float v = acc[i][j][r];
                if (MODE == 2) {
                    float dtv = softplus_(v + dt_bias[n]);
                    float u = (float)uref[(size_t)m * DI_ + n];
                    swg[(size_t)m * DI_ + n] = pack_bf2_(dtv * u, dtv);
                } else if (MODE == 4) {
                    if (n < 96)
                        pbuf[((size_t)blockIdx.x * CROWS_ + m) * 96 + n] = v;
                } else if (n < Nstore) {
                    if (addsrc) v += addsrc[(size_t)m * Nstore + n];
                    if (MODE == 1) Cb[(size_t)m * Nstore + n] = (bf16)v;
                    else           Cf[(size_t)m * Nstore + n] = v;
                }
            }
        }
    }
}

// reduce split-K partials -> dtr (bf16) + bc16 (bf16 pairs (B,C) per n)
__global__ __launch_bounds__(256) void xpost_kernel(const float* __restrict__ pbuf,
                                                    bf16* __restrict__ dtr,
                                                    bf16* __restrict__ bcb) {
    int idx = blockIdx.x * 256 + threadIdx.x;   // CROWS_*96
    int m = idx / 96, j = idx % 96;
    float s = pbuf[idx];
    #pragma unroll
    for (int k = 1; k < KS_; k++) s += pbuf[(size_t)k * CROWS_ * 96 + idx];
    if (j < 64) {
        dtr[(size_t)m * 64 + j] = (bf16)s;
    } else {
        int jj = j - 64;
        int n = jj & 15, hi = jj >> 4;    // hi=0 -> B, hi=1 -> C
        bcb[(size_t)m * 32 + 2 * n + hi] = (bf16)s;
    }
}

// ================= small prep kernels =================
__global__ __launch_bounds__(256) void cast_f2b_kernel(const float* __restrict__ s,
                                                       bf16* __restrict__ d) {
    size_t i = (size_t)blockIdx.x * 256 + threadIdx.x;
    d[i] = (bf16)s[i];
}

__global__ __launch_bounds__(256) void pad_lm_kernel(const float* __restrict__ s, bf16* __restrict__ d) {
    int i = blockIdx.x * 256 + threadIdx.x;     // 128*768
    int row = i / D_;
    d[i] = (row < V_) ? (bf16)s[i] : (bf16)0.f;
}

__global__ __launch_bounds__(256) void pad_embw_kernel(const float* __restrict__ s, bf16* __restrict__ d) {
    int i = blockIdx.x * 256 + threadIdx.x;     // 768*96
    int row = i / KE_, col = i % KE_;
    d[i] = (col < 2 * S_) ? (bf16)s[row * 2 * S_ + col] : (bf16)0.f;
}

__global__ __launch_bounds__(256) void feats_kernel(const float* __restrict__ x,
                                                    const int* __restrict__ mask,
                                                    bf16* __restrict__ d) {
    size_t i = (size_t)blockIdx.x * 256 + threadIdx.x;  // ROWS_*96
    size_t row = i / KE_;
    int col = (int)(i % KE_);
    float v = 0.f;
    if (col < S_) v = x[row * S_ + col];
    else if (col < 2 * S_) v = (float)mask[row * S_ + (col - S_)];
    d[i] = (bf16)v;
}

// x_proj padded+remapped: (NL,128,1536) rows: 0..47=dt_r, 48..63=0, 64..95=B|C, 96..127=0
__global__ __launch_bounds__(256) void xpw_pad_kernel(const float* __restrict__ xpw,
                                                      bf16* __restrict__ d) {
    int l = blockIdx.y;
    int idx = blockIdx.x * 256 + threadIdx.x;   // 128*1536
    int row = idx / DI_, col = idx % DI_;
    float v = 0.f;
    if (row < DTR_) v = xpw[((size_t)l * (DTR_ + 2 * N_) + row) * DI_ + col];
    else if (row >= 64 && row < 96) v = xpw[((size_t)l * (DTR_ + 2 * N_) + row - 16) * DI_ + col];
    d[(size_t)l * 128 * DI_ + idx] = (bf16)v;
}

// dt_proj_w padded: (NL,1536,64), cols 48..63 = 0
__global__ __launch_bounds__(256) void dtw_pad_kernel(const float* __restrict__ dtw,
                                                      bf16* __restrict__ d) {
    int l = blockIdx.y;
    int idx = blockIdx.x * 256 + threadIdx.x;   // 1536*64
    int row = idx / 64, c = idx % 64;
    float v = (c < DTR_) ? dtw[((size_t)l * DI_ + row) * DTR_ + c] : 0.f;
    d[(size_t)l * DI_ * 64 + idx] = (bf16)v;
}

__global__ __launch_bounds__(256) void sstat_kernel(const float* __restrict__ stat,
                                                    const float* __restrict__ static_w,
                                                    const float* __restrict__ static_b,
                                                    const float* __restrict__ emb_b,
                                                    float* __restrict__ sstat) {
    int i = blockIdx.x * 256 + threadIdx.x;  // B_*D_
    int d = i % D_, b = i / D_;
    float acc = emb_b[d] + static_b[d];
    const float* sw = static_w + (size_t)d * STATIC_;
    const float* sv = stat + (size_t)b * STATIC_;
    #pragma unroll
    for (int s = 0; s < STATIC_; s++) acc += sv[s] * sw[s];
    sstat[i] = acc;
}

__device__ __forceinline__ void block_reduce2_(float& a, float& b, float* sbuf) {
    #pragma unroll
    for (int off = 32; off > 0; off >>= 1) {
        a += __shfl_down(a, off, 64);
        b += __shfl_down(b, off, 64);
    }
    int lane = threadIdx.x & 63, wid = threadIdx.x >> 6;
    if (lane == 0) { sbuf[wid] = a; sbuf[4 + wid] = b; }
    __syncthreads();
    a = sbuf[0] + sbuf[1] + sbuf[2] + sbuf[3];
    b = sbuf[4] + sbuf[5] + sbuf[6] + sbuf[7];
}

__global__ __launch_bounds__(256) void ln_embed_kernel(const float* __restrict__ h_pre,
                                                       const float* __restrict__ sstat,
                                                       const float* __restrict__ ln_w,
                                                       const float* __restrict__ ln_b,
                                                       float* __restrict__ h) {
    int row = blockIdx.x, b = row / L_, tid = threadIdx.x;
    __shared__ float sbuf[8];
    float v[3], sum = 0.f, sq = 0.f;
    #pragma unroll
    for (int j = 0; j < 3; j++) {
        int d = tid + 256 * j;
        v[j] = h_pre[(size_t)row * D_ + d] + sstat[b * D_ + d];
        sum += v[j]; sq += v[j] * v[j];
    }
    block_reduce2_(sum, sq, sbuf);
    float mu = sum * (1.f / D_);
    float rstd = rsqrtf(sq * (1.f / D_) - mu * mu + 1e-5f);
    #pragma unroll
    for (int j = 0; j < 3; j++) {
        int d = tid + 256 * j;
        h[(size_t)row * D_ + d] = (v[j] - mu) * rstd * ln_w[d] + ln_b[d];
    }
}

__global__ __launch_bounds__(256) void rmsnorm_bf_kernel(const float* __restrict__ h,
                                                         const float* __restrict__ w,
                                                         bf16* __restrict__ out) {
    int row = blockIdx.x, tid = threadIdx.x;
    __shared__ float sbuf[8];
    float v[3], ss = 0.f, dummy = 0.f;
    #pragma unroll
    for (int j = 0; j < 3; j++) {
        v[j] = h[(size_t)row * D_ + tid + 256 * j];
        ss += v[j] * v[j];
    }
    block_reduce2_(ss, dummy, sbuf);
    float rstd = rsqrtf(ss * (1.f / D_) + 1e-5f);
    #pragma unroll
    for (int j = 0; j < 3; j++) {
        int d = tid + 256 * j;
        out[(size_t)row * D_ + d] = (bf16)(v[j] * rstd * w[d]);
    }
}

// conv K=4 + silu -> xc (4 channels/thread) ; gate u32 per (row,d) -> gag
__global__ __launch_bounds__(256) void conv_silu_kernel(const bf16* __restrict__ xzb,
                                                        const float* __restrict__ cw,
                                                        const float* __restrict__ cb,
                                                        const float* __restrict__ Dp,
                                                        bf16* __restrict__ xcb,
                                                        unsigned* __restrict__ gag) {
    size_t idx = (size_t)blockIdx.x * 256 + threadIdx.x;   // CROWS_*DI_/4
    int d4 = (int)(idx % (DI_ / 4));
    size_t row = idx / (DI_ / 4);
    int t = (int)(row % L_);
    int d = d4 * 4;
    const uint2* xz64 = (const uint2*)xzb;                 // row stride 768 uint2
    size_t base = row * 768 + d4;
    uint2 z2{0u, 0u};
    uint2 p0  = xz64[base];
    uint2 pm1 = (t >= 1) ? xz64[base - 768]     : z2;
    uint2 pm2 = (t >= 2) ? xz64[base - 2 * 768] : z2;
    uint2 pm3 = (t >= 3) ? xz64[base - 3 * 768] : z2;
    uint2 pz  = xz64[base + 384];

    bf16x4 a0 = __builtin_bit_cast(bf16x4, p0);
    bf16x4 a1 = __builtin_bit_cast(bf16x4, pm1);
    bf16x4 a2 = __builtin_bit_cast(bf16x4, pm2);
    bf16x4 a3 = __builtin_bit_cast(bf16x4, pm3);
    bf16x4 az = __builtin_bit_cast(bf16x4, pz);

    float cbl[4], Dl[4];
    *(float4*)cbl = ((const float4*)cb)[d4];
    *(float4*)Dl  = ((const float4*)Dp)[d4];

    float u[4];
    unsigned gv[4];
    #pragma unroll
    for (int c = 0; c < 4; c++) {
        float4 wc = ((const float4*)cw)[d + c];
        float acc = cbl[c] + wc.x * (float)a3[c] + wc.y * (float)a2[c]
                           + wc.z * (float)a1[c] + wc.w * (float)a0[c];
        u[c] = silu_(acc);
        float gz = silu_((float)az[c]);
        gv[c] = pack_bf2_(Dl[c] * u[c] * gz, gz);
    }
    ((uint2*)xcb)[row * (DI_ / 4) + d4] = uint2{pack_bf2_(u[0], u[1]), pack_bf2_(u[2], u[3])};
    *(uint4*)(gag + row * DI_ + d) = uint4{gv[0], gv[1], gv[2], gv[3]};
}

// ============== single-pass scan: u32 streams, one b128 = 4 timesteps ==============
__global__ __launch_bounds__(256) void scan_lds_kernel(const unsigned* __restrict__ bcp,
                                                       const unsigned* __restrict__ swg,
                                                       const unsigned* __restrict__ gag,
                                                       const float* __restrict__ A_log,
                                                       bf16* __restrict__ yb) {
    __shared__ unsigned lsw[2][16][TP4_];
    __shared__ unsigned lga[2][16][TP4_];
    __shared__ unsigned lbc[2][16][TP4_];
    const int tid = threadIdx.x;
    const int n = tid & 15, dl = tid >> 4;
    const int d = blockIdx.x * 16 + dl;
    const int b = blockIdx.y;
    const float AvL = -__expf(A_log[(size_t)d * N_ + n]) * 1.44269504f;
    const size_t seqbase = (size_t)b * L_;
    const int d0 = blockIdx.x * 16;

    unsigned swr[4], gar[4], bcr[4];

    #define GLOAD(c)                                                        \
        {                                                                   \
            size_t rb = seqbase + (size_t)(c) * TCH_;                       \
            _Pragma("unroll")                                               \
            for (int i = 0; i < 4; i++) {                                   \
                size_t g = rb + i * 16 + dl;                                \
                swr[i] = swg[g * DI_ + d0 + n];                             \
                gar[i] = gag[g * DI_ + d0 + n];                             \
                bcr[i] = bcp[g * 16 + n];                                   \
            }                                                               \
        }
    #define DSWRITE(p)                                                      \
        {                                                                   \
            _Pragma("unroll")                                               \
            for (int i = 0; i < 4; i++) {                                   \
                int t = i * 16 + dl;                                        \
                lsw[p][n][t] = swr[i];                                      \
                lga[p][n][t] = gar[i];                                      \
                lbc[p][n][t] = bcr[i];                                      \
            }                                                               \
        }

    GLOAD(0);
    DSWRITE(0);
    __syncthreads();
    GLOAD(1);

    float h = 0.f;
    for (int c = 0; c < NCHT_; c++) {
        int p = c & 1;
        bf16* py = yb + (seqbase + (size_t)c * TCH_) * DI_ + d;
        #pragma unroll 4
        for (int t0 = 0; t0 < TCH_; t0 += 4) {
            uint4 s4 = *(const uint4*)&lsw[p][dl][t0];
            uint4 b4 = *(const uint4*)&lbc[p][n][t0];
            uint4 g4{0u, 0u, 0u, 0u};
            if (n == 0) g4 = *(const uint4*)&lga[p][dl][t0];
            unsigned ss[4] = {s4.x, s4.y, s4.z, s4.w};
            unsigned bb[4] = {b4.x, b4.y, b4.z, b4.w};
            unsigned gg[4] = {g4.x, g4.y, g4.z, g4.w};
            #pragma unroll
            for (int u = 0; u < 4; u++) {
                bf16x2 dv = __builtin_bit_cast(bf16x2, ss[u]);
                bf16x2 bcv = __builtin_bit_cast(bf16x2, bb[u]);
                float du = (float)dv.x, dtv = (float)dv.y;
                float dA = __builtin_amdgcn_exp2f(dtv * AvL);
                h = dA * h + du * (float)bcv.x;
                float pq = h * (float)bcv.y;
                pq = dpp_add_<0xB1>(pq);
                pq = dpp_add_<0x4E>(pq);
                pq = dpp_add_<0x124>(pq);
                pq = dpp_add_<0x128>(pq);
                if (n == 0) {
                    bf16x2 og = __builtin_bit_cast(bf16x2, gg[u]);
                    py[(size_t)(t0 + u) * DI_] = (bf16)(pq * (float)og.y + (float)og.x);
                }
            }
        }
        if (c + 1 < NCHT_) {
            DSWRITE(p ^ 1);
            __syncthreads();
            if (c + 2 < NCHT_) GLOAD(c + 2);
        }
    }
    #undef GLOAD
    #undef DSWRITE
}

extern "C" void kernel_launch(void* const* d_in, const int* in_sizes, int n_in,
                              void* d_out, int out_size, void* d_ws, size_t ws_size,
                              hipStream_t stream) {
    const float* x        = (const float*)d_in[0];
    const float* stat     = (const float*)d_in[1];
    const int*   mask     = (const int*)d_in[3];
    const float* emb_w    = (const float*)d_in[5];
    const float* emb_b    = (const float*)d_in[6];
    const float* static_w = (const float*)d_in[7];
    const float* static_b = (const float*)d_in[8];
    const float* ln_w     = (const float*)d_in[9];
    const float* ln_b     = (const float*)d_in[10];
    const float* norm_w   = (const float*)d_in[11];
    const float* in_proj_w  = (const float*)d_in[12];
    const float* conv_w   = (const float*)d_in[13];
    const float* conv_b   = (const float*)d_in[14];
    const float* x_proj_w = (const float*)d_in[15];
    const float* dt_proj_w= (const float*)d_in[16];
    const float* dt_proj_b= (const float*)d_in[17];
    const float* A_log    = (const float*)d_in[18];
    const float* D_param  = (const float*)d_in[19];
    const float* out_proj_w = (const float*)d_in[20];
    const float* norm_f_w = (const float*)d_in[21];
    const float* lm_head_w= (const float*)d_in[22];
    float* out = (float*)d_out;

    // ---- workspace layout (bytes), total ~190 MB ----
    char* p = (char*)d_ws;
    float*    h      = (float*)p;         p += (size_t)ROWS_ * D_ * 4;          // 50.3 MB
    bf16*     hn_bf  = (bf16*)p;          p += (size_t)CROWS_ * D_ * 2;         // 6.3
    char*     xz_region = p;                                                    // h_pre alias start
    bf16*     xz_bf  = (bf16*)p;          p += (size_t)CROWS_ * 2 * DI_ * 2;    // 25.2
    bf16*     xc_bf  = (bf16*)p;          p += (size_t)CROWS_ * DI_ * 2;        // 12.6
    unsigned* sw_g   = (unsigned*)p;      p += (size_t)CROWS_ * DI_ * 4;        // 25.2
    unsigned* gate_g = (unsigned*)p;      p += (size_t)CROWS_ * DI_ * 4;        // 25.2
    bf16*     bc16   = (bf16*)p;          p += (size_t)CROWS_ * 32 * 2;         // 0.26
    bf16*     dtr_bf = (bf16*)p;          p += (size_t)CROWS_ * 64 * 2;         // 0.5
    float*    pbuf   = (float*)p;         p += (size_t)KS_ * CROWS_ * 96 * 4;   // 6.3
    bf16*     y_bf   = (bf16*)p;          p += (size_t)ROWS_ * DI_ * 2;         // 50.3 (FULL batch)
    bf16*     inw_l  = (bf16*)p;          p += (size_t)2 * DI_ * D_ * 2;        // 4.7 (per-layer)
    bf16*     outw_l = (bf16*)p;          p += (size_t)D_ * DI_ * 2;            // 2.4 (per-layer)
    bf16*     xpwp_bf= (bf16*)p;          p += (size_t)NL_ * 128 * DI_ * 2;     // 1.6
    bf16*     dtwp_bf= (bf16*)p;          p += (size_t)NL_ * DI_ * 64 * 2;      // 0.8
    bf16*     lmw_bf = (bf16*)p;          p += (size_t)128 * D_ * 2;
    bf16*     embw_bf= (bf16*)p;          p += (size_t)D_ * KE_ * 2;
    bf16*     feats  = (bf16*)p;          p += (size_t)ROWS_ * KE_ * 2;         // 3.1
    float*    sstat  = (float*)p;         p += (size_t)B_ * D_ * 4;
    float*    h_pre  = (float*)xz_region; // 50.3 MB alias over xz/xc/sw_g (dead then)
    bf16*     hn_full= (bf16*)sw_g;       // 25.2 MB alias (sw_g dead at final stage)

    // ---- weight prep ----
    pad_lm_kernel<<<(128 * D_) / 256, 256, 0, stream>>>(lm_head_w, lmw_bf);
    pad_embw_kernel<<<(D_ * KE_) / 256, 256, 0, stream>>>(emb_w, embw_bf);
    feats_kernel<<<(ROWS_ * KE_) / 256, 256, 0, stream>>>(x, mask, feats);
    dim3 gxp((128 * DI_) / 256, NL_);
    xpw_pad_kernel<<<gxp, 256, 0, stream>>>(x_proj_w, xpwp_bf);
    dim3 gdt((DI_ * 64) / 256, NL_);
    dtw_pad_kernel<<<gdt, 256, 0, stream>>>(dt_proj_w, dtwp_bf);
    sstat_kernel<<<(B_ * D_) / 256, 256, 0, stream>>>(stat, static_w, static_b, emb_b, sstat);

    // ---- embed + LN ----
    gemm_mfma<0><<<(D_ / 128) * (ROWS_ / 128), 256, 0, stream>>>(
        feats, embw_bf, nullptr, h_pre, D_, KE_, D_ / 128,
        nullptr, nullptr, nullptr, nullptr);
    ln_embed_kernel<<<ROWS_, 256, 0, stream>>>(h_pre, sstat, ln_w, ln_b, h);

    // ---- layers ----
    for (int l = 0; l < NL_; l++) {
        cast_f2b_kernel<<<(2 * DI_ * D_) / 256, 256, 0, stream>>>(
            in_proj_w + (size_t)l * 2 * DI_ * D_, inw_l);
        cast_f2b_kernel<<<(D_ * DI_) / 256, 256, 0, stream>>>(
            out_proj_w + (size_t)l * D_ * DI_, outw_l);

        for (int c = 0; c < NCH_; c++) {
            float* hc = h + (size_t)c * CROWS_ * D_;

            rmsnorm_bf_kernel<<<CROWS_, 256, 0, stream>>>(hc, norm_w + (size_t)l * D_, hn_bf);

            gemm_mfma<1><<<(2 * DI_ / 128) * (CROWS_ / 128), 256, 0, stream>>>(
                hn_bf, inw_l, nullptr, xz_bf, 2 * DI_, D_, 2 * DI_ / 128,
                nullptr, nullptr, nullptr, nullptr);

            conv_silu_kernel<<<(CROWS_ * DI_ / 4) / 256, 256, 0, stream>>>(
                xz_bf, conv_w + (size_t)l * DI_ * 4, conv_b + (size_t)l * DI_,
                D_param + (size_t)l * DI_, xc_bf, gate_g);

            dim3 g2a(KS_, CROWS_ / 128);
            gemm_mfma<4><<<g2a, 256, 0, stream>>>(xc_bf, xpwp_bf + (size_t)l * 128 * DI_,
                                                  nullptr, nullptr, 0, DI_, 1,
                                                  nullptr, nullptr, pbuf, nullptr);
            xpost_kernel<<<(CROWS_ * 96) / 256, 256, 0, stream>>>(pbuf, dtr_bf, bc16);

            gemm_mfma<2><<<(DI_ / 128) * (CROWS_ / 128), 256, 0, stream>>>(
                dtr_bf, dtwp_bf + (size_t)l * DI_ * 64, nullptr, nullptr, 0, 64, DI_ / 128,
                dt_proj_b + (size_t)l * DI_, sw_g, nullptr, xc_bf);

            dim3 gs(DI_ / 16, CB_);
            scan_lds_kernel<<<gs, 256, 0, stream>>>((const unsigned*)bc16, sw_g, gate_g,
                                                    A_log + (size_t)l * DI_ * N_,
                                                    y_bf + (size_t)c * CROWS_ * DI_);
        }

        gemm_mfma<0><<<(D_ / 128) * (ROWS_ / 128), 256, 0, stream>>>(
            y_bf, outw_l, h, h, D_, DI_, D_ / 128,
            nullptr, nullptr, nullptr, nullptr);
    }

    // ---- final rmsnorm + lm_head (full batch) ----
    rmsnorm_bf_kernel<<<ROWS_, 256, 0, stream>>>(h, norm_f_w, hn_full);
    gemm_mfma<0><<<ROWS_ / 128, 256, 0, stream>>>(
        hn_full, lmw_bf, nullptr, out, V_, D_, 1,
        nullptr, nullptr, nullptr, nullptr);
}